// Round 2
// baseline (961.377 us; speedup 1.0000x reference)
//
#include <hip/hip_runtime.h>
#include <stdint.h>

#define NN 2048
#define BB 64
#define FF 66
#define ROWE (BB*FF)       // 4224 elems per node-row
#define ROWU2 (ROWE/4)     // 1056 uint2 (4 bf16 each)
#define NCH 6
#define CHU2 (ROWU2/NCH)   // 176
#define EE 65536
#define APITCH 360         // padded LDS K-pitch (352 used + 8 pad)

typedef unsigned short u16;
typedef __bf16 bf16x8 __attribute__((ext_vector_type(8)));
typedef float f32x4 __attribute__((ext_vector_type(4)));

__device__ __forceinline__ float bf2f(u16 h){ return __uint_as_float(((unsigned)h)<<16); }
__device__ __forceinline__ u16 f2bf(float f){
  unsigned u = __float_as_uint(f);
  u += 0x7fffu + ((u>>16)&1u);
  return (u16)(u>>16);
}
// boundary load: bfflag=1 -> external tensor is bf16, else float32
__device__ __forceinline__ float loadf(const void* p, size_t i, int bfflag){
  return bfflag ? bf2f(((const u16*)p)[i]) : ((const float*)p)[i];
}

// Decide external float dtype from vals1 (uniform in [0,1/32)).
// bf16: every u16 is a small-positive bf16 encoding in [0x2800,0x3D80).
// f32:  the low u16 of each word is uniform mantissa garbage (~8% in range).
__global__ void probe_k(const unsigned* __restrict__ vals, int* __restrict__ flag){
  int cnt = 0;
  for (int i=0;i<64;i++){
    unsigned lo = vals[i] & 0xffffu;
    if (lo >= 0x2800u && lo < 0x3D80u) cnt++;
  }
  *flag = (cnt >= 32) ? 1 : 0;
}

__global__ void hist_k(const int* __restrict__ rows, int* __restrict__ cnt){
  int e = blockIdx.x*256 + threadIdx.x;
  atomicAdd(&cnt[rows[e]], 1);
}

__global__ void scan_k(const int* __restrict__ cnt, int* __restrict__ rp, int* __restrict__ cur){
  __shared__ int s[1024];
  int t = threadIdx.x;
  int c0 = cnt[2*t], c1 = cnt[2*t+1];
  int ps = c0 + c1;
  s[t] = ps;
  __syncthreads();
  for (int off=1; off<1024; off<<=1){
    int v = (t>=off) ? s[t-off] : 0;
    __syncthreads();
    s[t] += v;
    __syncthreads();
  }
  int excl = s[t] - ps;
  rp[2*t] = excl;  cur[2*t] = excl;
  rp[2*t+1] = excl + c0;  cur[2*t+1] = excl + c0;
  if (t==0) rp[2048] = EE;
}

__global__ void scatter_k(const int* __restrict__ rows, const int* __restrict__ cols,
                          const void* __restrict__ vals, int* __restrict__ cur,
                          int2* __restrict__ scv, const int* __restrict__ flag){
  int bfflag = *flag;
  int e = blockIdx.x*256 + threadIdx.x;
  int r = rows[e];
  int p = atomicAdd(&cur[r], 1);
  int2 cv; cv.x = cols[e]; cv.y = __float_as_int(loadf(vals, e, bfflag));
  scv[p] = cv;
}

// Pack W[(f*5+m)*O + o] into exact MFMA B-fragment order:
// Wf[((q*OT + t)*64 + L)*8 + j]  with o = t*16+(L&15), kk = q*32+(L>>4)*8+j, kk = m*66+f
__global__ void pack_w_k(const void* __restrict__ W, u16* __restrict__ Wf, int O, int OT,
                         const int* __restrict__ flag){
  int bfflag = *flag;
  int i = blockIdx.x*256 + threadIdx.x;
  int j = i & 7, L = (i>>3)&63, tq = i>>9;
  int t = tq % OT, q = tq / OT;
  int o = t*16 + (L&15);
  int kk = q*32 + (L>>4)*8 + j;
  float v = 0.f;
  if (kk < 330){ int m = kk/66, f = kk - m*66; v = loadf(W, (size_t)(f*5+m)*O + o, bfflag); }
  Wf[i] = f2bf(v);
}

__global__ void build_x0_k(const void* __restrict__ inp, const void* __restrict__ st,
                           u16* __restrict__ X0, const int* __restrict__ flag){
  int bfflag = *flag;
  int n = blockIdx.x;
  for (int i = threadIdx.x; i < ROWE; i += 256){
    int b = i/FF, f = i - b*FF;
    float v = (f<2) ? loadf(inp, (size_t)b*(NN*2) + n*2 + f, bfflag)
                    : loadf(st,  (size_t)b*(NN*64) + n*64 + (f-2), bfflag);
    X0[(size_t)n*ROWE + i] = f2bf(v);
  }
}

// dst[n, chunk] = alpha * sum_e val_e * src[col_e, chunk]  (+ beta * other[n, chunk])
__global__ __launch_bounds__(64) void spmm_k(const u16* __restrict__ src, const u16* __restrict__ other,
            u16* __restrict__ dst, const int* __restrict__ rp, const int2* __restrict__ scv,
            float alpha, float beta){
  int n = blockIdx.x, ch = blockIdx.y, tid = threadIdx.x;
  int e0 = rp[n], e1 = rp[n+1];
  float acc[3][4] = {};
  const size_t cb = (size_t)ch * CHU2;
  for (int e=e0; e<e1; ++e){
    int2 cv = scv[e];
    const uint2* p = (const uint2*)(src + (size_t)cv.x*ROWE) + cb;
    float v = __int_as_float(cv.y);
    #pragma unroll
    for (int it=0; it<3; ++it){
      int i = tid + it*64;
      if (i < CHU2){
        uint2 d = p[i];
        acc[it][0] += v*__uint_as_float(d.x<<16);
        acc[it][1] += v*__uint_as_float(d.x & 0xffff0000u);
        acc[it][2] += v*__uint_as_float(d.y<<16);
        acc[it][3] += v*__uint_as_float(d.y & 0xffff0000u);
      }
    }
  }
  uint2* q = (uint2*)(dst + (size_t)n*ROWE) + cb;
  const uint2* ot = other ? (const uint2*)(other + (size_t)n*ROWE) + cb : nullptr;
  #pragma unroll
  for (int it=0; it<3; ++it){
    int i = tid + it*64;
    if (i < CHU2){
      float r0 = alpha*acc[it][0], r1 = alpha*acc[it][1];
      float r2 = alpha*acc[it][2], r3 = alpha*acc[it][3];
      if (ot){
        uint2 d = ot[i];
        r0 += beta*__uint_as_float(d.x<<16);
        r1 += beta*__uint_as_float(d.x & 0xffff0000u);
        r2 += beta*__uint_as_float(d.y<<16);
        r3 += beta*__uint_as_float(d.y & 0xffff0000u);
      }
      uint2 w;
      w.x = (unsigned)f2bf(r0) | ((unsigned)f2bf(r1)<<16);
      w.y = (unsigned)f2bf(r2) | ((unsigned)f2bf(r3)<<16);
      q[i] = w;
    }
  }
}

// One block per node n. A-tile [64b x 352k] in LDS (k = m*66+f, zero-padded to 352).
// MODE 0 (gate, OT=8): sigmoid; o<64 -> overwrite X0 state slice with r*state;
//                      o>=64 -> stash u into d_out (same index the cand epilogue owns).
// MODE 1 (cand, OT=4): c = tanh; new_state = u*state + (1-u)*c into d_out.
template<int OT, int MODE>
__global__ __launch_bounds__(256) void gemm_k(
    const u16* __restrict__ Xa, const u16* __restrict__ Xb, const u16* __restrict__ Xc,
    const u16* __restrict__ Xd, const u16* __restrict__ Xe,
    const u16* __restrict__ Wf, const void* __restrict__ bias,
    const void* __restrict__ state, u16* __restrict__ X0w, void* __restrict__ outp,
    const int* __restrict__ flag){
  __shared__ __align__(16) u16 A[64*APITCH];
  int tid = threadIdx.x, n = blockIdx.x;
  int bfflag = *flag;
  #pragma unroll
  for (int m=0;m<5;m++){
    const u16* Xm = (m==0)?Xa:(m==1)?Xb:(m==2)?Xc:(m==3)?Xd:Xe;
    const uint4* src = (const uint4*)(Xm + (size_t)n*ROWE);
    for (int r = tid; r < 528; r += 256){
      union { uint4 v; u16 h[8]; } u;
      u.v = src[r];
      int g = r*8;
      int b = g/66, f = g - b*66;
      #pragma unroll
      for (int j=0;j<8;j++){
        A[b*APITCH + m*66 + f] = u.h[j];
        f++;
        if (f==66){ f=0; b++; }
      }
    }
  }
  for (int i = tid; i < 64*22; i += 256){
    int b = i/22, kk = 330 + (i - b*22);
    A[b*APITCH + kk] = 0;
  }
  __syncthreads();
  int lane = tid & 63, w = tid >> 6;
  int m16 = lane & 15, q4 = lane >> 4;
  f32x4 acc[OT];
  #pragma unroll
  for (int t=0;t<OT;t++) acc[t] = (f32x4){0.f,0.f,0.f,0.f};
  const u16* arow = A + (w*16 + m16)*APITCH + q4*8;
  const bf16x8* wp = (const bf16x8*)Wf;
  #pragma unroll
  for (int q=0;q<11;q++){
    bf16x8 af = *((const bf16x8*)(arow + q*32));
    #pragma unroll
    for (int t=0;t<OT;t++){
      bf16x8 bfr = wp[(q*OT+t)*64 + lane];
      acc[t] = __builtin_amdgcn_mfma_f32_16x16x32_bf16(af, bfr, acc[t], 0, 0, 0);
    }
  }
  #pragma unroll
  for (int t=0;t<OT;t++){
    int o = t*16 + m16;
    float bo = loadf(bias, o, bfflag);
    #pragma unroll
    for (int r=0;r<4;r++){
      int b = w*16 + q4*4 + r;
      float x = acc[t][r] + bo;
      if (MODE==0){
        float s = 1.f/(1.f + __expf(-x));
        if (o < 64){
          float st = loadf(state, (size_t)b*(NN*64) + n*64 + o, bfflag);
          X0w[((size_t)n*64 + b)*66 + 2 + o] = f2bf(s*st);
        } else {
          size_t idx = (size_t)b*(NN*64) + n*64 + (o-64);
          if (bfflag) ((u16*)outp)[idx] = f2bf(s); else ((float*)outp)[idx] = s;
        }
      } else {
        float c = tanhf(x);
        size_t idx = (size_t)b*(NN*64) + n*64 + o;
        float uu = bfflag ? bf2f(((const u16*)outp)[idx]) : ((const float*)outp)[idx];
        float st = loadf(state, idx, bfflag);
        float ns = uu*st + (1.f-uu)*c;
        if (bfflag) ((u16*)outp)[idx] = f2bf(ns); else ((float*)outp)[idx] = ns;
      }
    }
  }
}

extern "C" void kernel_launch(void* const* d_in, const int* in_sizes, int n_in,
                              void* d_out, int out_size, void* d_ws, size_t ws_size,
                              hipStream_t stream) {
  const void* inputs = d_in[0];
  const void* state  = d_in[1];
  const int* edges1 = (const int*)d_in[2];
  const void* vals1  = d_in[3];
  const int* edges2 = (const int*)d_in[4];
  const void* vals2  = d_in[5];
  const void* Wg     = d_in[6];
  const void* bg     = d_in[7];
  const void* Wc     = d_in[8];
  const void* bc     = d_in[9];

  char* ws = (char*)d_ws;
  size_t off = 0;
  auto get = [&](size_t bytes)->void*{
    void* p = ws + off; off = (off + bytes + 255) & ~(size_t)255; return p;
  };
  const size_t XBYTES = (size_t)NN*ROWE*2;   // 17,301,504 each
  u16* X0  = (u16*)get(XBYTES);
  u16* X1  = (u16*)get(XBYTES);
  u16* X2  = (u16*)get(XBYTES);
  u16* X3  = (u16*)get(XBYTES);
  u16* X4  = (u16*)get(XBYTES);
  u16* Wfg = (u16*)get(11*8*64*8*2);
  u16* Wfc = (u16*)get(11*4*64*8*2);
  int* cnt  = (int*)get(2*2048*4);
  int* rp1  = (int*)get(2049*4);
  int* rp2  = (int*)get(2049*4);
  int* cur1 = (int*)get(2048*4);
  int* cur2 = (int*)get(2048*4);
  int* flag = (int*)get(4);
  int2* scv1 = (int2*)get((size_t)EE*8);
  int2* scv2 = (int2*)get((size_t)EE*8);
  // total ~87.9 MB

  probe_k<<<1,1,0,stream>>>((const unsigned*)vals1, flag);
  hipMemsetAsync(cnt, 0, 2*2048*4, stream);
  hist_k<<<256,256,0,stream>>>(edges1, cnt);
  hist_k<<<256,256,0,stream>>>(edges2, cnt+2048);
  scan_k<<<1,1024,0,stream>>>(cnt,      rp1, cur1);
  scan_k<<<1,1024,0,stream>>>(cnt+2048, rp2, cur2);
  scatter_k<<<256,256,0,stream>>>(edges1, edges1+EE, vals1, cur1, scv1, flag);
  scatter_k<<<256,256,0,stream>>>(edges2, edges2+EE, vals2, cur2, scv2, flag);
  pack_w_k<<<176,256,0,stream>>>(Wg, Wfg, 128, 8, flag);
  pack_w_k<<<88,256,0,stream>>>(Wc, Wfc, 64, 4, flag);
  build_x0_k<<<NN,256,0,stream>>>(inputs, state, X0, flag);

  dim3 sg(NN, NCH);
  // gate diffusion
  spmm_k<<<sg,64,0,stream>>>(X0, nullptr, X1, rp1, scv1, 1.f,  0.f);
  spmm_k<<<sg,64,0,stream>>>(X1, X0,      X2, rp1, scv1, 2.f, -1.f);
  spmm_k<<<sg,64,0,stream>>>(X0, nullptr, X3, rp2, scv2, 1.f,  0.f);
  spmm_k<<<sg,64,0,stream>>>(X3, X0,      X4, rp2, scv2, 2.f, -1.f);
  // gate GEMM: writes r*state into X0's state slice, u into d_out
  gemm_k<8,0><<<NN,256,0,stream>>>(X0,X1,X2,X3,X4, Wfg, bg, state, X0, d_out, flag);
  // candidate diffusion (X0 now = [inputs, r*state])
  spmm_k<<<sg,64,0,stream>>>(X0, nullptr, X1, rp1, scv1, 1.f,  0.f);
  spmm_k<<<sg,64,0,stream>>>(X1, X0,      X2, rp1, scv1, 2.f, -1.f);
  spmm_k<<<sg,64,0,stream>>>(X0, nullptr, X3, rp2, scv2, 1.f,  0.f);
  spmm_k<<<sg,64,0,stream>>>(X3, X0,      X4, rp2, scv2, 2.f, -1.f);
  gemm_k<4,1><<<NN,256,0,stream>>>(X0,X1,X2,X3,X4, Wfc, bc, state, X0, d_out, flag);
}

// Round 3
// 576.830 us; speedup vs baseline: 1.6667x; 1.6667x over previous
//
#include <hip/hip_runtime.h>
#include <stdint.h>

#define NN 2048
#define BB 64
#define FF 66
#define ROWE (BB*FF)       // 4224 bf16 per node-row
#define ROWU4 528          // uint4 (8 bf16) per row
#define CHU4 66            // uint4 per chunk (8 chunks, 1056 B each)
#define EE 65536
#define APITCH 360         // padded LDS K-pitch (352 used + 8 pad)

typedef unsigned short u16;
typedef __bf16 bf16x8 __attribute__((ext_vector_type(8)));
typedef float f32x4 __attribute__((ext_vector_type(4)));

__device__ __forceinline__ float bf2f(u16 h){ return __uint_as_float(((unsigned)h)<<16); }
__device__ __forceinline__ u16 f2bf(float f){
  unsigned u = __float_as_uint(f);
  u += 0x7fffu + ((u>>16)&1u);
  return (u16)(u>>16);
}
__device__ __forceinline__ float loadf(const void* p, size_t i, int bfflag){
  return bfflag ? bf2f(((const u16*)p)[i]) : ((const float*)p)[i];
}
__device__ __forceinline__ void acc8(float v, uint4 d, float* a){
  a[0] += v*__uint_as_float(d.x<<16); a[1] += v*__uint_as_float(d.x&0xffff0000u);
  a[2] += v*__uint_as_float(d.y<<16); a[3] += v*__uint_as_float(d.y&0xffff0000u);
  a[4] += v*__uint_as_float(d.z<<16); a[5] += v*__uint_as_float(d.z&0xffff0000u);
  a[6] += v*__uint_as_float(d.w<<16); a[7] += v*__uint_as_float(d.w&0xffff0000u);
}
__device__ __forceinline__ uint4 pack8(const float* r){
  uint4 w;
  w.x = (unsigned)f2bf(r[0]) | ((unsigned)f2bf(r[1])<<16);
  w.y = (unsigned)f2bf(r[2]) | ((unsigned)f2bf(r[3])<<16);
  w.z = (unsigned)f2bf(r[4]) | ((unsigned)f2bf(r[5])<<16);
  w.w = (unsigned)f2bf(r[6]) | ((unsigned)f2bf(r[7])<<16);
  return w;
}

// dtype probe: vals1 ~ U[0,1/32). bf16 -> every u16 in [0x2800,0x3D80); f32 low-u16 ~uniform.
__global__ void probe_k(const unsigned* __restrict__ vals, int* __restrict__ flag){
  int cnt = 0;
  for (int i=0;i<64;i++){
    unsigned lo = vals[i] & 0xffffu;
    if (lo >= 0x2800u && lo < 0x3D80u) cnt++;
  }
  *flag = (cnt >= 32) ? 1 : 0;
}

__global__ void hist2_k(const int* __restrict__ e1, const int* __restrict__ e2,
                        int* __restrict__ cnt){
  int b = blockIdx.x;
  if (b < 256) atomicAdd(&cnt[e1[b*256 + threadIdx.x]], 1);
  else atomicAdd(&cnt[2048 + e2[(b-256)*256 + threadIdx.x]], 1);
}

__global__ void scan2_k(const int* __restrict__ cntA, int* __restrict__ rpA, int* __restrict__ curA){
  __shared__ int s[1024];
  const int* cnt = cntA + blockIdx.x*2048;
  int* rp  = rpA  + blockIdx.x*2049;
  int* cur = curA + blockIdx.x*2048;
  int t = threadIdx.x;
  int c0 = cnt[2*t], c1 = cnt[2*t+1];
  int ps = c0 + c1;
  s[t] = ps;
  __syncthreads();
  for (int off=1; off<1024; off<<=1){
    int v = (t>=off) ? s[t-off] : 0;
    __syncthreads();
    s[t] += v;
    __syncthreads();
  }
  int excl = s[t] - ps;
  rp[2*t] = excl;  cur[2*t] = excl;
  rp[2*t+1] = excl + c0;  cur[2*t+1] = excl + c0;
  if (t==0) rp[2048] = EE;
}

__global__ void scatter2_k(const int* __restrict__ e1, const void* __restrict__ v1,
                           const int* __restrict__ e2, const void* __restrict__ v2,
                           int* __restrict__ curA, int2* __restrict__ scvA,
                           const int* __restrict__ flag){
  int bfflag = *flag;
  int b = blockIdx.x;
  const int* rows; const int* cols; const void* vals; int* cur; int2* scv; int e;
  if (b < 256){ rows=e1; cols=e1+EE; vals=v1; cur=curA; scv=scvA; e=b*256+threadIdx.x; }
  else { rows=e2; cols=e2+EE; vals=v2; cur=curA+2048; scv=scvA+EE; e=(b-256)*256+threadIdx.x; }
  int r = rows[e];
  int p = atomicAdd(&cur[r], 1);
  int2 cv; cv.x = cols[e]; cv.y = __float_as_int(loadf(vals, e, bfflag));
  scv[p] = cv;
}

// Pack W[(f*5+m)*O + o] into MFMA B-frag order:
// Wf[((q*OT+t)*64 + L)*8 + j], o = t*16+(L&15), kk = q*32+(L>>4)*8+j, kk = m*66+f
__global__ void pack2_k(const void* __restrict__ Wg, const void* __restrict__ Wc,
                        u16* __restrict__ Wfg, u16* __restrict__ Wfc,
                        const int* __restrict__ flag){
  int bfflag = *flag;
  int b = blockIdx.x;
  const void* W; u16* Wf; int O, OT, i;
  if (b < 176){ W=Wg; Wf=Wfg; O=128; OT=8; i=b*256+threadIdx.x; }
  else { W=Wc; Wf=Wfc; O=64; OT=4; i=(b-176)*256+threadIdx.x; }
  int j = i & 7, L = (i>>3)&63, tq = i>>9;
  int t = tq % OT, q = tq / OT;
  int o = t*16 + (L&15);
  int kk = q*32 + (L>>4)*8 + j;
  float v = 0.f;
  if (kk < 330){ int m = kk/66, f = kk - m*66; v = loadf(W, (size_t)(f*5+m)*O + o, bfflag); }
  Wf[i] = f2bf(v);
}

__global__ void build_x0_k(const void* __restrict__ inp, const void* __restrict__ st,
                           u16* __restrict__ X0, const int* __restrict__ flag){
  int bfflag = *flag;
  int n = blockIdx.x;
  for (int i = threadIdx.x; i < ROWE; i += 256){
    int b = i/FF, f = i - b*FF;
    float v = (f<2) ? loadf(inp, (size_t)b*(NN*2) + n*2 + f, bfflag)
                    : loadf(st,  (size_t)b*(NN*64) + n*64 + (f-2), bfflag);
    X0[(size_t)n*ROWE + i] = f2bf(v);
  }
}

// First Chebyshev hop for BOTH supports from common src X0.
// grid.x = NN*16: ch = bid&7 (-> XCD ch), n = (bid>>3)&2047, sup = bid>>14.
__global__ __launch_bounds__(64) void spmm_dual_k(
    const u16* __restrict__ src, u16* __restrict__ dstA, u16* __restrict__ dstB,
    const int* __restrict__ rpA, const int2* __restrict__ scvA){
  int bid = blockIdx.x;
  int ch = bid & 7, n = (bid >> 3) & (NN-1), sup = bid >> 14;
  const int* rp = rpA + sup*2049;
  const int2* scv = scvA + sup*EE;
  u16* dst = sup ? dstB : dstA;
  int tid = threadIdx.x;
  int e0 = rp[n], e1 = rp[n+1];
  float a0[8] = {0,0,0,0,0,0,0,0};
  float a1[8] = {0,0,0,0,0,0,0,0};
  const uint4* base = (const uint4*)src + ch*CHU4;
  int e = e0;
  for (; e+1 < e1; e += 2){
    int2 ca = scv[e], cb = scv[e+1];
    const uint4* pa = base + (size_t)ca.x*ROWU4;
    const uint4* pb = base + (size_t)cb.x*ROWU4;
    float va = __int_as_float(ca.y), vb = __int_as_float(cb.y);
    uint4 da = pa[tid], db = pb[tid];
    acc8(va, da, a0); acc8(vb, db, a0);
    if (tid < 2){
      uint4 ta = pa[64+tid], tb = pb[64+tid];
      acc8(va, ta, a1); acc8(vb, tb, a1);
    }
  }
  if (e < e1){
    int2 ca = scv[e];
    const uint4* pa = base + (size_t)ca.x*ROWU4;
    float va = __int_as_float(ca.y);
    acc8(va, pa[tid], a0);
    if (tid < 2) acc8(va, pa[64+tid], a1);
  }
  uint4* q = (uint4*)dst + (size_t)n*ROWU4 + ch*CHU4;
  q[tid] = pack8(a0);
  if (tid < 2) q[64+tid] = pack8(a1);
}

// Second hop: dst = 2*S@src - other. grid.x = NN*8: ch = bid&7, n = bid>>3.
__global__ __launch_bounds__(64) void spmm_cheb_k(
    const u16* __restrict__ src, const u16* __restrict__ other, u16* __restrict__ dst,
    const int* __restrict__ rp, const int2* __restrict__ scv){
  int bid = blockIdx.x;
  int ch = bid & 7, n = bid >> 3;
  int tid = threadIdx.x;
  int e0 = rp[n], e1 = rp[n+1];
  float a0[8] = {0,0,0,0,0,0,0,0};
  float a1[8] = {0,0,0,0,0,0,0,0};
  const uint4* base = (const uint4*)src + ch*CHU4;
  int e = e0;
  for (; e+1 < e1; e += 2){
    int2 ca = scv[e], cb = scv[e+1];
    const uint4* pa = base + (size_t)ca.x*ROWU4;
    const uint4* pb = base + (size_t)cb.x*ROWU4;
    float va = __int_as_float(ca.y), vb = __int_as_float(cb.y);
    uint4 da = pa[tid], db = pb[tid];
    acc8(va, da, a0); acc8(vb, db, a0);
    if (tid < 2){
      uint4 ta = pa[64+tid], tb = pb[64+tid];
      acc8(va, ta, a1); acc8(vb, tb, a1);
    }
  }
  if (e < e1){
    int2 ca = scv[e];
    const uint4* pa = base + (size_t)ca.x*ROWU4;
    float va = __int_as_float(ca.y);
    acc8(va, pa[tid], a0);
    if (tid < 2) acc8(va, pa[64+tid], a1);
  }
  const uint4* ot = (const uint4*)other + (size_t)n*ROWU4 + ch*CHU4;
  uint4* q = (uint4*)dst + (size_t)n*ROWU4 + ch*CHU4;
  {
    uint4 d = ot[tid];
    float r[8];
    r[0]=2.f*a0[0]-__uint_as_float(d.x<<16); r[1]=2.f*a0[1]-__uint_as_float(d.x&0xffff0000u);
    r[2]=2.f*a0[2]-__uint_as_float(d.y<<16); r[3]=2.f*a0[3]-__uint_as_float(d.y&0xffff0000u);
    r[4]=2.f*a0[4]-__uint_as_float(d.z<<16); r[5]=2.f*a0[5]-__uint_as_float(d.z&0xffff0000u);
    r[6]=2.f*a0[6]-__uint_as_float(d.w<<16); r[7]=2.f*a0[7]-__uint_as_float(d.w&0xffff0000u);
    q[tid] = pack8(r);
  }
  if (tid < 2){
    uint4 d = ot[64+tid];
    float r[8];
    r[0]=2.f*a1[0]-__uint_as_float(d.x<<16); r[1]=2.f*a1[1]-__uint_as_float(d.x&0xffff0000u);
    r[2]=2.f*a1[2]-__uint_as_float(d.y<<16); r[3]=2.f*a1[3]-__uint_as_float(d.y&0xffff0000u);
    r[4]=2.f*a1[4]-__uint_as_float(d.z<<16); r[5]=2.f*a1[5]-__uint_as_float(d.z&0xffff0000u);
    r[6]=2.f*a1[6]-__uint_as_float(d.w<<16); r[7]=2.f*a1[7]-__uint_as_float(d.w&0xffff0000u);
    q[64+tid] = pack8(r);
  }
}

// One block per node n. A-tile [64b x 352k] in LDS (k = m*66+f, zero-padded to 352).
// MODE 0 (gate, OT=8): sigmoid; o<64 -> overwrite X0 state slice with r*state;
//                      o>=64 -> stash u into d_out. MODE 1 (cand): GRU combine.
template<int OT, int MODE>
__global__ __launch_bounds__(256) void gemm_k(
    const u16* __restrict__ Xa, const u16* __restrict__ Xb, const u16* __restrict__ Xc,
    const u16* __restrict__ Xd, const u16* __restrict__ Xe,
    const u16* __restrict__ Wf, const void* __restrict__ bias,
    const void* __restrict__ state, u16* __restrict__ X0w, void* __restrict__ outp,
    const int* __restrict__ flag){
  __shared__ __align__(16) u16 A[64*APITCH];
  int tid = threadIdx.x, n = blockIdx.x;
  int bfflag = *flag;
  #pragma unroll
  for (int m=0;m<5;m++){
    const u16* Xm = (m==0)?Xa:(m==1)?Xb:(m==2)?Xc:(m==3)?Xd:Xe;
    const uint4* src = (const uint4*)(Xm + (size_t)n*ROWE);
    for (int r = tid; r < 528; r += 256){
      union { uint4 v; u16 h[8]; } u;
      u.v = src[r];
      int g = r*8;
      int b = g/66, f = g - b*66;
      #pragma unroll
      for (int j=0;j<8;j++){
        A[b*APITCH + m*66 + f] = u.h[j];
        f++;
        if (f==66){ f=0; b++; }
      }
    }
  }
  for (int i = tid; i < 64*22; i += 256){
    int b = i/22, kk = 330 + (i - b*22);
    A[b*APITCH + kk] = 0;
  }
  __syncthreads();
  int lane = tid & 63, w = tid >> 6;
  int m16 = lane & 15, q4 = lane >> 4;
  f32x4 acc[OT];
  #pragma unroll
  for (int t=0;t<OT;t++) acc[t] = (f32x4){0.f,0.f,0.f,0.f};
  const u16* arow = A + (w*16 + m16)*APITCH + q4*8;
  const bf16x8* wp = (const bf16x8*)Wf;
  #pragma unroll
  for (int q=0;q<11;q++){
    bf16x8 af = *((const bf16x8*)(arow + q*32));
    #pragma unroll
    for (int t=0;t<OT;t++){
      bf16x8 bfr = wp[(q*OT+t)*64 + lane];
      acc[t] = __builtin_amdgcn_mfma_f32_16x16x32_bf16(af, bfr, acc[t], 0, 0, 0);
    }
  }
  #pragma unroll
  for (int t=0;t<OT;t++){
    int o = t*16 + m16;
    float bo = loadf(bias, o, bfflag);
    #pragma unroll
    for (int r=0;r<4;r++){
      int b = w*16 + q4*4 + r;
      float x = acc[t][r] + bo;
      if (MODE==0){
        float s = 1.f/(1.f + __expf(-x));
        if (o < 64){
          float st = loadf(state, (size_t)b*(NN*64) + n*64 + o, bfflag);
          X0w[((size_t)n*64 + b)*66 + 2 + o] = f2bf(s*st);
        } else {
          size_t idx = (size_t)b*(NN*64) + n*64 + (o-64);
          if (bfflag) ((u16*)outp)[idx] = f2bf(s); else ((float*)outp)[idx] = s;
        }
      } else {
        float c = tanhf(x);
        size_t idx = (size_t)b*(NN*64) + n*64 + o;
        float uu = bfflag ? bf2f(((const u16*)outp)[idx]) : ((const float*)outp)[idx];
        float st = loadf(state, idx, bfflag);
        float ns = uu*st + (1.f-uu)*c;
        if (bfflag) ((u16*)outp)[idx] = f2bf(ns); else ((float*)outp)[idx] = ns;
      }
    }
  }
}

extern "C" void kernel_launch(void* const* d_in, const int* in_sizes, int n_in,
                              void* d_out, int out_size, void* d_ws, size_t ws_size,
                              hipStream_t stream) {
  const void* inputs = d_in[0];
  const void* state  = d_in[1];
  const int* edges1 = (const int*)d_in[2];
  const void* vals1  = d_in[3];
  const int* edges2 = (const int*)d_in[4];
  const void* vals2  = d_in[5];
  const void* Wg     = d_in[6];
  const void* bg     = d_in[7];
  const void* Wc     = d_in[8];
  const void* bc     = d_in[9];

  char* ws = (char*)d_ws;
  size_t off = 0;
  auto get = [&](size_t bytes)->void*{
    void* p = ws + off; off = (off + bytes + 255) & ~(size_t)255; return p;
  };
  const size_t XBYTES = (size_t)NN*ROWE*2;   // 17,301,504 each
  u16* X0  = (u16*)get(XBYTES);
  u16* X1  = (u16*)get(XBYTES);
  u16* X2  = (u16*)get(XBYTES);
  u16* X3  = (u16*)get(XBYTES);
  u16* X4  = (u16*)get(XBYTES);
  u16* Wfg = (u16*)get(11*8*64*8*2);
  u16* Wfc = (u16*)get(11*4*64*8*2);
  int* cnt  = (int*)get(2*2048*4);
  int* rp   = (int*)get(2*2049*4);
  int* cur  = (int*)get(2*2048*4);
  int* flag = (int*)get(4);
  int2* scv = (int2*)get((size_t)2*EE*8);

  probe_k<<<1,1,0,stream>>>((const unsigned*)vals1, flag);
  hipMemsetAsync(cnt, 0, 2*2048*4, stream);
  hist2_k<<<512,256,0,stream>>>(edges1, edges2, cnt);
  scan2_k<<<2,1024,0,stream>>>(cnt, rp, cur);
  scatter2_k<<<512,256,0,stream>>>(edges1, vals1, edges2, vals2, cur, scv, flag);
  pack2_k<<<264,256,0,stream>>>(Wg, Wc, Wfg, Wfc, flag);
  build_x0_k<<<NN,256,0,stream>>>(inputs, state, X0, flag);

  // gate diffusion
  spmm_dual_k<<<NN*16,64,0,stream>>>(X0, X1, X3, rp, scv);
  spmm_cheb_k<<<NN*8,64,0,stream>>>(X1, X0, X2, rp,        scv);
  spmm_cheb_k<<<NN*8,64,0,stream>>>(X3, X0, X4, rp+2049,   scv+EE);
  gemm_k<8,0><<<NN,256,0,stream>>>(X0,X1,X2,X3,X4, Wfg, bg, state, X0, d_out, flag);
  // candidate diffusion (X0 now = [inputs, r*state])
  spmm_dual_k<<<NN*16,64,0,stream>>>(X0, X1, X3, rp, scv);
  spmm_cheb_k<<<NN*8,64,0,stream>>>(X1, X0, X2, rp,        scv);
  spmm_cheb_k<<<NN*8,64,0,stream>>>(X3, X0, X4, rp+2049,   scv+EE);
  gemm_k<4,1><<<NN,256,0,stream>>>(X0,X1,X2,X3,X4, Wfc, bc, state, X0, d_out, flag);
}

// Round 4
// 474.020 us; speedup vs baseline: 2.0281x; 1.2169x over previous
//
#include <hip/hip_runtime.h>
#include <stdint.h>

#define NN 2048
#define BB 64
#define EE 65536
#define APITCH 360         // padded LDS K-pitch (352 used + 8 pad)
#define XSN ((size_t)NN*4096)   // elems per XS matrix [N][64][64]
#define XIN ((size_t)NN*128)    // elems per XI matrix [N][64][2]

typedef unsigned short u16;
typedef __bf16 bf16x8 __attribute__((ext_vector_type(8)));
typedef float f32x4 __attribute__((ext_vector_type(4)));
typedef float f32x2 __attribute__((ext_vector_type(2)));

__device__ __forceinline__ float bf2f(u16 h){ return __uint_as_float(((unsigned)h)<<16); }
__device__ __forceinline__ u16 f2bf(float f){
  unsigned u = __float_as_uint(f);
  u += 0x7fffu + ((u>>16)&1u);
  return (u16)(u>>16);
}
__device__ __forceinline__ float loadf(const void* p, size_t i, int bfflag){
  return bfflag ? bf2f(((const u16*)p)[i]) : ((const float*)p)[i];
}
__device__ __forceinline__ f32x2 up2(unsigned u){
  f32x2 r; r.x = __uint_as_float(u<<16); r.y = __uint_as_float(u & 0xffff0000u); return r;
}
__device__ __forceinline__ unsigned pk2(f32x2 t){
  return (unsigned)f2bf(t.x) | ((unsigned)f2bf(t.y)<<16);
}
__device__ __forceinline__ void accv(float v, uint4 d, f32x2* a){
  f32x2 vv = {v, v};
  a[0] += vv*up2(d.x); a[1] += vv*up2(d.y);
  a[2] += vv*up2(d.z); a[3] += vv*up2(d.w);
}

// dtype probe: vals1 ~ U[0,1/32). bf16 -> every u16 in [0x2800,0x3D80); f32 low-u16 ~uniform.
__global__ void probe_k(const unsigned* __restrict__ vals, int* __restrict__ flag){
  int cnt = 0;
  for (int i=0;i<64;i++){
    unsigned lo = vals[i] & 0xffffu;
    if (lo >= 0x2800u && lo < 0x3D80u) cnt++;
  }
  *flag = (cnt >= 32) ? 1 : 0;
}

__global__ void hist2_k(const int* __restrict__ e1, const int* __restrict__ e2,
                        int* __restrict__ cnt){
  int b = blockIdx.x;
  if (b < 256) atomicAdd(&cnt[e1[b*256 + threadIdx.x]], 1);
  else atomicAdd(&cnt[2048 + e2[(b-256)*256 + threadIdx.x]], 1);
}

__global__ void scan2_k(const int* __restrict__ cntA, int* __restrict__ rpA, int* __restrict__ curA){
  __shared__ int s[1024];
  const int* cnt = cntA + blockIdx.x*2048;
  int* rp  = rpA  + blockIdx.x*2049;
  int* cur = curA + blockIdx.x*2048;
  int t = threadIdx.x;
  int c0 = cnt[2*t], c1 = cnt[2*t+1];
  int ps = c0 + c1;
  s[t] = ps;
  __syncthreads();
  for (int off=1; off<1024; off<<=1){
    int v = (t>=off) ? s[t-off] : 0;
    __syncthreads();
    s[t] += v;
    __syncthreads();
  }
  int excl = s[t] - ps;
  rp[2*t] = excl;  cur[2*t] = excl;
  rp[2*t+1] = excl + c0;  cur[2*t+1] = excl + c0;
  if (t==0) rp[2048] = EE;
}

__global__ void scatter2_k(const int* __restrict__ e1, const void* __restrict__ v1,
                           const int* __restrict__ e2, const void* __restrict__ v2,
                           int* __restrict__ curA, int2* __restrict__ scvA,
                           const int* __restrict__ flag){
  int bfflag = *flag;
  int b = blockIdx.x;
  const int* rows; const int* cols; const void* vals; int* cur; int2* scv; int e;
  if (b < 256){ rows=e1; cols=e1+EE; vals=v1; cur=curA; scv=scvA; e=b*256+threadIdx.x; }
  else { rows=e2; cols=e2+EE; vals=v2; cur=curA+2048; scv=scvA+EE; e=(b-256)*256+threadIdx.x; }
  int r = rows[e];
  int p = atomicAdd(&cur[r], 1);
  int2 cv; cv.x = cols[e]; cv.y = __float_as_int(loadf(vals, e, bfflag));
  scv[p] = cv;
}

// Pack W[(f*5+m)*O + o] into MFMA B-frag order:
// Wf[((q*OT+t)*64 + L)*8 + j], o = t*16+(L&15), kk = q*32+(L>>4)*8+j, kk = m*66+f
__global__ void pack2_k(const void* __restrict__ Wg, const void* __restrict__ Wc,
                        u16* __restrict__ Wfg, u16* __restrict__ Wfc,
                        const int* __restrict__ flag){
  int bfflag = *flag;
  int b = blockIdx.x;
  const void* W; u16* Wf; int O, OT, i;
  if (b < 176){ W=Wg; Wf=Wfg; O=128; OT=8; i=b*256+threadIdx.x; }
  else { W=Wc; Wf=Wfc; O=64; OT=4; i=(b-176)*256+threadIdx.x; }
  int j = i & 7, L = (i>>3)&63, tq = i>>9;
  int t = tq % OT, q = tq / OT;
  int o = t*16 + (L&15);
  int kk = q*32 + (L>>4)*8 + j;
  float v = 0.f;
  if (kk < 330){ int m = kk/66, f = kk - m*66; v = loadf(W, (size_t)(f*5+m)*O + o, bfflag); }
  Wf[i] = f2bf(v);
}

__global__ void build_x0_k(const void* __restrict__ inp, const void* __restrict__ st,
                           u16* __restrict__ XSb, u16* __restrict__ XIb,
                           const int* __restrict__ flag){
  int bfflag = *flag, n = blockIdx.x, tid = threadIdx.x;
  if (bfflag){
    const uint4* sp = (const uint4*)st;
    uint4* xp = (uint4*)(XSb + (size_t)n*4096);
    #pragma unroll
    for (int it=0; it<2; ++it){
      int r = tid + it*256;     // [0,512): b = r>>3, v4 = r&7
      int b = r>>3, v4 = r&7;
      xp[r] = sp[(size_t)b*(NN*8) + (size_t)n*8 + v4];
    }
    if (tid < 64){
      ((unsigned*)XIb)[n*64 + tid] = ((const unsigned*)inp)[(size_t)tid*NN + n];
    }
  } else {
    for (int i=tid; i<4096; i+=256){
      int b=i>>6, f=i&63;
      XSb[(size_t)n*4096+i] = f2bf(((const float*)st)[(size_t)b*(NN*64) + n*64 + f]);
    }
    for (int i=tid; i<128; i+=256){
      int b=i>>1, f=i&1;
      XIb[(size_t)n*128+i] = f2bf(((const float*)inp)[(size_t)b*(NN*2) + n*2 + f]);
    }
  }
}

// Diffusion hop for BOTH supports (sup = blockIdx.y).
// CHEB=0: X_dst = S X0        (src m=0, dst m = sup?3:1)
// CHEB=1: X_dst = 2 S X_src - X0  (src m = sup?3:1, dst m = sup?4:2)
// grid.x = NN*8 (XS chunks, ch=bx&7 pins chunk->XCD) + NN/2 (XI half-wave blocks).
template<int CHEB>
__global__ __launch_bounds__(64) void spmm_k(
    u16* __restrict__ XSb, u16* __restrict__ XIb,
    const int* __restrict__ rpA, const int2* __restrict__ scvA){
  int sup = blockIdx.y;
  const int* rp = rpA + sup*2049;
  const int2* scv = scvA + sup*EE;
  const int srcm = CHEB ? (sup?3:1) : 0;
  const int dstm = CHEB ? (sup?4:2) : (sup?3:1);
  int tid = threadIdx.x;
  int bx = blockIdx.x;
  if (bx < NN*8){
    int ch = bx & 7, n = bx >> 3;
    int e0 = rp[n], e1 = rp[n+1];
    const uint4* src = (const uint4*)(XSb + srcm*XSN);
    int off = ch*64 + tid;
    f32x2 a[4] = {{0.f,0.f},{0.f,0.f},{0.f,0.f},{0.f,0.f}};
    int e = e0;
    for (; e+3 < e1; e += 4){
      int2 c0=scv[e], c1=scv[e+1], c2=scv[e+2], c3=scv[e+3];
      uint4 d0 = src[((size_t)c0.x<<9) + off];
      uint4 d1 = src[((size_t)c1.x<<9) + off];
      uint4 d2 = src[((size_t)c2.x<<9) + off];
      uint4 d3 = src[((size_t)c3.x<<9) + off];
      accv(__int_as_float(c0.y), d0, a);
      accv(__int_as_float(c1.y), d1, a);
      accv(__int_as_float(c2.y), d2, a);
      accv(__int_as_float(c3.y), d3, a);
    }
    for (; e < e1; ++e){
      int2 c0 = scv[e];
      accv(__int_as_float(c0.y), src[((size_t)c0.x<<9) + off], a);
    }
    uint4* dst = (uint4*)(XSb + dstm*XSN);
    uint4 w;
    if (CHEB){
      uint4 o = ((const uint4*)XSb)[((size_t)n<<9) + off];
      f32x2 t;
      t = 2.f*a[0] - up2(o.x); w.x = pk2(t);
      t = 2.f*a[1] - up2(o.y); w.y = pk2(t);
      t = 2.f*a[2] - up2(o.z); w.z = pk2(t);
      t = 2.f*a[3] - up2(o.w); w.w = pk2(t);
    } else {
      w.x = pk2(a[0]); w.y = pk2(a[1]); w.z = pk2(a[2]); w.w = pk2(a[3]);
    }
    dst[((size_t)n<<9) + off] = w;
  } else {
    // XI part: 2 nodes per block, half-wave each; 32 uint2 per row.
    int idx = bx - NN*8;
    int n = idx*2 + (tid>>5), m = tid & 31;
    int e0 = rp[n], e1 = rp[n+1];
    const uint2* src = (const uint2*)(XIb + srcm*XIN);
    f32x2 a0 = {0.f,0.f}, a1 = {0.f,0.f};
    for (int e=e0; e<e1; ++e){
      int2 cv = scv[e];
      uint2 d = src[cv.x*32 + m];
      f32x2 vv = {__int_as_float(cv.y), __int_as_float(cv.y)};
      a0 += vv*up2(d.x); a1 += vv*up2(d.y);
    }
    uint2* dst = (uint2*)(XIb + dstm*XIN);
    if (CHEB){
      uint2 o = ((const uint2*)XIb)[n*32 + m];
      a0 = 2.f*a0 - up2(o.x); a1 = 2.f*a1 - up2(o.y);
    }
    uint2 w; w.x = pk2(a0); w.y = pk2(a1);
    dst[n*32 + m] = w;
  }
}

// One block per node n. A-tile [64b x 352k] in LDS (k = m*66 + f; f0,1 from XI, f2..65 from XS).
// MODE 0 (gate, OT=8): sigmoid; o<64 -> overwrite XS0 with r*state; o>=64 -> stash u in d_out.
// MODE 1 (cand, OT=4): c = tanh; new_state = u*state + (1-u)*c into d_out.
template<int OT, int MODE>
__global__ __launch_bounds__(256) void gemm_k(
    u16* __restrict__ XSb, const u16* __restrict__ XIb,
    const u16* __restrict__ Wf, const void* __restrict__ bias,
    const void* __restrict__ state, void* __restrict__ outp,
    const int* __restrict__ flag){
  __shared__ __align__(16) u16 A[64*APITCH];
  unsigned* A32 = (unsigned*)A;
  int tid = threadIdx.x, n = blockIdx.x;
  int bfflag = *flag;
  #pragma unroll
  for (int m=0;m<5;m++){
    const uint4* src = (const uint4*)(XSb + (size_t)m*XSN + ((size_t)n<<12));
    #pragma unroll
    for (int it=0; it<2; ++it){
      int r = tid + it*256;
      uint4 d = src[r];
      int b = r>>3, f0 = (r&7)*8;
      int o2 = (b*APITCH + m*66 + 2 + f0) >> 1;
      A32[o2+0]=d.x; A32[o2+1]=d.y; A32[o2+2]=d.z; A32[o2+3]=d.w;
    }
  }
  for (int i=tid; i<320; i+=256){
    int m = i>>6, b = i&63;
    unsigned v = ((const unsigned*)(XIb + (size_t)m*XIN))[n*64 + b];
    A32[(b*APITCH + m*66)>>1] = v;
  }
  for (int i=tid; i<64*11; i+=256){
    int b = i/11, j = i - b*11;
    A32[((b*APITCH + 330)>>1) + j] = 0;
  }
  __syncthreads();
  int lane = tid & 63, w = tid >> 6;
  int m16 = lane & 15, q4 = lane >> 4;
  f32x4 acc[OT];
  #pragma unroll
  for (int t=0;t<OT;t++) acc[t] = (f32x4){0.f,0.f,0.f,0.f};
  const u16* arow = A + (w*16 + m16)*APITCH + q4*8;
  const bf16x8* wp = (const bf16x8*)Wf;
  #pragma unroll
  for (int q=0;q<11;q++){
    bf16x8 af = *((const bf16x8*)(arow + q*32));
    #pragma unroll
    for (int t=0;t<OT;t++){
      bf16x8 bfr = wp[(q*OT+t)*64 + lane];
      acc[t] = __builtin_amdgcn_mfma_f32_16x16x32_bf16(af, bfr, acc[t], 0, 0, 0);
    }
  }
  #pragma unroll
  for (int t=0;t<OT;t++){
    int o = t*16 + m16;
    float bo = loadf(bias, o, bfflag);
    #pragma unroll
    for (int r=0;r<4;r++){
      int b = w*16 + q4*4 + r;
      float x = acc[t][r] + bo;
      if (MODE==0){
        float s = 1.f/(1.f + __expf(-x));
        if (o < 64){
          float st = loadf(state, (size_t)b*(NN*64) + n*64 + o, bfflag);
          XSb[((size_t)n<<12) + b*64 + o] = f2bf(s*st);
        } else {
          size_t idx = (size_t)b*(NN*64) + n*64 + (o-64);
          if (bfflag) ((u16*)outp)[idx] = f2bf(s); else ((float*)outp)[idx] = s;
        }
      } else {
        float c = tanhf(x);
        size_t idx = (size_t)b*(NN*64) + n*64 + o;
        float uu = bfflag ? bf2f(((const u16*)outp)[idx]) : ((const float*)outp)[idx];
        float st = loadf(state, idx, bfflag);
        float ns = uu*st + (1.f-uu)*c;
        if (bfflag) ((u16*)outp)[idx] = f2bf(ns); else ((float*)outp)[idx] = ns;
      }
    }
  }
}

extern "C" void kernel_launch(void* const* d_in, const int* in_sizes, int n_in,
                              void* d_out, int out_size, void* d_ws, size_t ws_size,
                              hipStream_t stream) {
  const void* inputs = d_in[0];
  const void* state  = d_in[1];
  const int* edges1 = (const int*)d_in[2];
  const void* vals1  = d_in[3];
  const int* edges2 = (const int*)d_in[4];
  const void* vals2  = d_in[5];
  const void* Wg     = d_in[6];
  const void* bg     = d_in[7];
  const void* Wc     = d_in[8];
  const void* bc     = d_in[9];

  char* ws = (char*)d_ws;
  size_t off = 0;
  auto get = [&](size_t bytes)->void*{
    void* p = ws + off; off = (off + bytes + 255) & ~(size_t)255; return p;
  };
  u16* XSb = (u16*)get(5*XSN*2);   // 83.9 MB
  u16* XIb = (u16*)get(5*XIN*2);   // 2.6 MB
  u16* Wfg = (u16*)get(11*8*64*8*2);
  u16* Wfc = (u16*)get(11*4*64*8*2);
  int* cnt  = (int*)get(2*2048*4);
  int* rp   = (int*)get(2*2049*4);
  int* cur  = (int*)get(2*2048*4);
  int* flag = (int*)get(4);
  int2* scv = (int2*)get((size_t)2*EE*8);

  probe_k<<<1,1,0,stream>>>((const unsigned*)vals1, flag);
  hipMemsetAsync(cnt, 0, 2*2048*4, stream);
  hist2_k<<<512,256,0,stream>>>(edges1, edges2, cnt);
  scan2_k<<<2,1024,0,stream>>>(cnt, rp, cur);
  scatter2_k<<<512,256,0,stream>>>(edges1, vals1, edges2, vals2, cur, scv, flag);
  pack2_k<<<264,256,0,stream>>>(Wg, Wc, Wfg, Wfc, flag);
  build_x0_k<<<NN,256,0,stream>>>(inputs, state, XSb, XIb, flag);

  dim3 sg(NN*8 + NN/2, 2);
  // gate diffusion
  spmm_k<0><<<sg,64,0,stream>>>(XSb, XIb, rp, scv);
  spmm_k<1><<<sg,64,0,stream>>>(XSb, XIb, rp, scv);
  gemm_k<8,0><<<NN,256,0,stream>>>(XSb, XIb, Wfg, bg, state, d_out, flag);
  // candidate diffusion (XS0 now = r*state, XI0 = inputs)
  spmm_k<0><<<sg,64,0,stream>>>(XSb, XIb, rp, scv);
  spmm_k<1><<<sg,64,0,stream>>>(XSb, XIb, rp, scv);
  gemm_k<4,1><<<NN,256,0,stream>>>(XSb, XIb, Wfc, bc, state, d_out, flag);
}